// Round 4
// baseline (549.486 us; speedup 1.0000x reference)
//
#include <hip/hip_runtime.h>

#define N_NODES 100000
#define N_EDGES 3200000
#define F_IN    128
#define HIDDEN  16
#define F_OUT   2

#define BSZ     128                  // nodes per bucket
#define NB      782                  // ceil(N_NODES / BSZ)
#define G       1024                 // edge-partition blocks for hist/scatter
#define EPB     (N_EDGES / G)        // 3125 edges per partition (exact)
#define SPLIT   4                    // blocks per bucket in agg1/agg2
#define DUMMY_E 100000u              // sentinel adj entry: dl=0, src=row 100000 (zeroed)

// ---------- P1: per-partition bucket histogram ----------
__global__ __launch_bounds__(256) void k_hist(const int* __restrict__ dst,
                                              unsigned* __restrict__ blockHist) {
    __shared__ unsigned hist[NB];
    int t = threadIdx.x, g = blockIdx.x;
    for (int i = t; i < NB; i += 256) hist[i] = 0u;
    __syncthreads();
    int base = g * EPB;
    for (int i = t; i < EPB; i += 256) atomicAdd(&hist[dst[base + i] >> 7], 1u);
    __syncthreads();
    for (int i = t; i < NB; i += 256) blockHist[i * G + g] = hist[i];
}

// ---------- P2: per-bucket exclusive scan over partitions ----------
__global__ __launch_bounds__(G) void k_scan_blocks(unsigned* __restrict__ blockHist,
                                                   unsigned* __restrict__ total) {
    __shared__ unsigned s[G];
    int b = blockIdx.x, t = threadIdx.x;
    unsigned v = blockHist[b * G + t];
    s[t] = v;
    __syncthreads();
    for (int off = 1; off < G; off <<= 1) {
        unsigned xv = (t >= off) ? s[t - off] : 0u;
        __syncthreads();
        s[t] += xv;
        __syncthreads();
    }
    blockHist[b * G + t] = s[t] - v;
    if (t == G - 1) total[b] = s[t];
}

// ---------- P2c: exclusive scan of bucket totals ----------
__global__ __launch_bounds__(1024) void k_scan_buckets(const unsigned* __restrict__ total,
                                                       unsigned* __restrict__ bucketBase) {
    __shared__ unsigned s[1024];
    int t = threadIdx.x;
    unsigned v = (t < NB) ? total[t] : 0u;
    s[t] = v;
    __syncthreads();
    for (int off = 1; off < 1024; off <<= 1) {
        unsigned xv = (t >= off) ? s[t - off] : 0u;
        __syncthreads();
        s[t] += xv;
        __syncthreads();
    }
    if (t < NB) bucketBase[t] = s[t] - v;
    if (t == 1023) bucketBase[NB] = s[t];
}

// ---------- P3: scatter into bucket-sorted adjacency ----------
// entry: (dst & 127) << 17 | src
__global__ __launch_bounds__(256) void k_scatter(const int* __restrict__ src,
                                                 const int* __restrict__ dst,
                                                 const unsigned* __restrict__ blockHist,
                                                 const unsigned* __restrict__ bucketBase,
                                                 unsigned* __restrict__ adj) {
    __shared__ unsigned cur[NB];
    int t = threadIdx.x, g = blockIdx.x;
    for (int i = t; i < NB; i += 256) cur[i] = bucketBase[i] + blockHist[i * G + g];
    __syncthreads();
    int base = g * EPB;
    for (int i = t; i < EPB; i += 256) {
        int s = src[base + i], d = dst[base + i];
        unsigned pos = atomicAdd(&cur[d >> 7], 1u);
        adj[pos] = ((unsigned)(d & 127) << 17) | (unsigned)s;
    }
}

// ---------- P4: degree (incl. self-loop) -> dinv ----------
__global__ __launch_bounds__(256) void k_degree(const unsigned* __restrict__ adj,
                                                const unsigned* __restrict__ bucketBase,
                                                float* __restrict__ dinv) {
    __shared__ unsigned deg[BSZ];
    int b = blockIdx.x, t = threadIdx.x;
    if (t < BSZ) deg[t] = 0u;
    __syncthreads();
    int e0 = (int)bucketBase[b], e1 = (int)bucketBase[b + 1];
    for (int i = e0 + t; i < e1; i += 256) atomicAdd(&deg[adj[i] >> 17], 1u);
    __syncthreads();
    if (t < BSZ) {
        int n = b * BSZ + t;
        if (n < N_NODES) dinv[n] = rsqrtf((float)(deg[t] + 1u));
    }
}

// ---------- layer-1 GEMM: hs = racc = (x @ W1) * dinv ----------
#define MM1_NODES 64
#define SXP 132
__global__ __launch_bounds__(256) void k_mm1(const float* __restrict__ x,
                                             const float* __restrict__ W1,
                                             const float* __restrict__ dinv,
                                             float4* __restrict__ hs,
                                             float4* __restrict__ racc) {
    __shared__ float sW[F_IN * HIDDEN];       // 8 KB
    __shared__ float sX[MM1_NODES * SXP];     // 33 KB
    int t = threadIdx.x;
    for (int i = t; i < F_IN * HIDDEN; i += 256) sW[i] = W1[i];
    int node0 = blockIdx.x * MM1_NODES;
    const float4* xv = (const float4*)(x + (size_t)node0 * F_IN);
    int maxv = (N_NODES - node0) * (F_IN / 4);
    if (maxv < 0) maxv = 0;
    for (int i = t; i < MM1_NODES * (F_IN / 4); i += 256) {
        if (i < maxv) {
            int nl = i >> 5, f4 = i & 31;
            ((float4*)(sX + nl * SXP))[f4] = xv[i];
        }
    }
    __syncthreads();
    int lane4 = t & 3;
    int nl = t >> 2;
    int n = node0 + nl;
    if (n >= NB * BSZ) return;
    if (n >= N_NODES) {                       // zero pad rows incl. DUMMY row 100000
        float4 z = {0.f, 0.f, 0.f, 0.f};
        hs[(size_t)n * 4 + lane4] = z;
        racc[(size_t)n * 4 + lane4] = z;
        return;
    }
    const float4* sWv = (const float4*)sW;
    float4 a = {0.f, 0.f, 0.f, 0.f};
    #pragma unroll 8
    for (int f = 0; f < F_IN; ++f) {
        float xval = sX[nl * SXP + f];
        float4 w = sWv[f * 4 + lane4];
        a.x = fmaf(xval, w.x, a.x);
        a.y = fmaf(xval, w.y, a.y);
        a.z = fmaf(xval, w.z, a.z);
        a.w = fmaf(xval, w.w, a.w);
    }
    float dv = dinv[n];
    a.x *= dv; a.y *= dv; a.z *= dv; a.w *= dv;
    hs[(size_t)n * 4 + lane4] = a;
    racc[(size_t)n * 4 + lane4] = a;          // self-loop init; agg1 accumulates on top
}

// ---------- layer-1 aggregation: ping-pong pipelined gather + LDS accumulate ----------
#define ACC1S 17                              // padded row stride (floats)
__global__ __launch_bounds__(256) void k_agg1(const unsigned* __restrict__ adj,
                                              const unsigned* __restrict__ bucketBase,
                                              const float4* __restrict__ hs,
                                              float* __restrict__ racc) {
    __shared__ float acc[BSZ * ACC1S];        // 8.5 KB
    int t = threadIdx.x;
    int b = blockIdx.x >> 2, s = blockIdx.x & (SPLIT - 1);
    for (int i = t; i < BSZ * ACC1S; i += 256) acc[i] = 0.f;
    __syncthreads();
    int e0 = (int)bucketBase[b], e1 = (int)bucketBase[b + 1];
    int len = e1 - e0;
    int chunk = (len + SPLIT - 1) >> 2;
    int cs = e0 + s * chunk;
    int ce = cs + chunk; if (ce > e1) ce = e1;
    if (ce > cs) {
        int lane4 = t & 3;
        int base = cs + (t >> 2);             // 4 lanes per edge, 64 slots, batch stride 512
        int nb = (ce - cs + 511) >> 9;        // batches of 8 edges/thread (512/block)

#define LD1(dst, k, u) { int p = base + 512 * (k) + 64 * (u); dst = (p < ce) ? adj[p] : DUMMY_E; }
#define GA1(dst, vsrc) dst = hs[(size_t)((vsrc) & 0x1FFFFu) * 4 + lane4];
#define AT1(vsrc, val) { unsigned dl = (vsrc) >> 17; float* row = &acc[dl * ACC1S + lane4 * 4]; \
    atomicAdd(&row[0], (val).x); atomicAdd(&row[1], (val).y); \
    atomicAdd(&row[2], (val).z); atomicAdd(&row[3], (val).w); }
#define LDB1(P, k) LD1(P##0, k, 0) LD1(P##1, k, 1) LD1(P##2, k, 2) LD1(P##3, k, 3) \
                   LD1(P##4, k, 4) LD1(P##5, k, 5) LD1(P##6, k, 6) LD1(P##7, k, 7)
#define GAB1(V, P) GA1(V##0, P##0) GA1(V##1, P##1) GA1(V##2, P##2) GA1(V##3, P##3) \
                   GA1(V##4, P##4) GA1(V##5, P##5) GA1(V##6, P##6) GA1(V##7, P##7)
#define ATB1(P, V) AT1(P##0, V##0) AT1(P##1, V##1) AT1(P##2, V##2) AT1(P##3, V##3) \
                   AT1(P##4, V##4) AT1(P##5, V##5) AT1(P##6, V##6) AT1(P##7, V##7)

        unsigned ia0, ia1, ia2, ia3, ia4, ia5, ia6, ia7;
        unsigned ib0, ib1, ib2, ib3, ib4, ib5, ib6, ib7;
        float4 va0, va1, va2, va3, va4, va5, va6, va7;
        float4 vb0, vb1, vb2, vb3, vb4, vb5, vb6, vb7;

        LDB1(ia, 0)
        int k = 0;
        for (;;) {
            GAB1(va, ia)                       // gathers batch k (A)
            __builtin_amdgcn_sched_barrier(0);
            LDB1(ib, k + 1)                    // prefetch idx batch k+1 (B)
            __builtin_amdgcn_sched_barrier(0);
            ATB1(ia, va)                       // commit batch k
            ++k; if (k >= nb) break;
            GAB1(vb, ib)
            __builtin_amdgcn_sched_barrier(0);
            LDB1(ia, k + 1)
            __builtin_amdgcn_sched_barrier(0);
            ATB1(ib, vb)
            ++k; if (k >= nb) break;
        }
    }
    __syncthreads();
    float* rb = racc + (size_t)b * (BSZ * HIDDEN);
    for (int idx = t; idx < BSZ * HIDDEN; idx += 256)
        atomicAdd(&rb[idx], acc[(idx >> 4) * ACC1S + (idx & 15)]);
}

// ---------- layer 2: relu/bias + 16->2 GEMM, pre-scaled by dinv ----------
__global__ __launch_bounds__(256) void k_mm2(const float* __restrict__ racc,
                                             const float* __restrict__ b1,
                                             const float* __restrict__ W2,
                                             const float* __restrict__ dinv,
                                             float2* __restrict__ hs2,
                                             float2* __restrict__ racc2) {
    int n = blockIdx.x * 256 + threadIdx.x;
    if (n >= NB * BSZ) return;
    if (n >= N_NODES) {                        // zero pad rows incl. DUMMY
        float2 z = {0.f, 0.f};
        hs2[n] = z;
        return;
    }
    float dv = dinv[n];
    float a0 = 0.f, a1 = 0.f;
    #pragma unroll
    for (int kk = 0; kk < HIDDEN; ++kk) {
        float v = fmaxf(fmaf(dv, racc[(size_t)n * HIDDEN + kk], b1[kk]), 0.f);
        a0 = fmaf(v, W2[kk * F_OUT + 0], a0);
        a1 = fmaf(v, W2[kk * F_OUT + 1], a1);
    }
    float2 h2; h2.x = a0 * dv; h2.y = a1 * dv;
    hs2[n] = h2;
    racc2[n] = h2;
}

// ---------- layer-2 aggregation: same pipeline, 1 lane/edge, float2 ----------
#define ACC2S 3
__global__ __launch_bounds__(256) void k_agg2(const unsigned* __restrict__ adj,
                                              const unsigned* __restrict__ bucketBase,
                                              const float2* __restrict__ hs2,
                                              float* __restrict__ racc2) {
    __shared__ float acc[BSZ * ACC2S];
    int t = threadIdx.x;
    int b = blockIdx.x >> 2, s = blockIdx.x & (SPLIT - 1);
    for (int i = t; i < BSZ * ACC2S; i += 256) acc[i] = 0.f;
    __syncthreads();
    int e0 = (int)bucketBase[b], e1 = (int)bucketBase[b + 1];
    int len = e1 - e0;
    int chunk = (len + SPLIT - 1) >> 2;
    int cs = e0 + s * chunk;
    int ce = cs + chunk; if (ce > e1) ce = e1;
    if (ce > cs) {
        int base = cs + t;                     // 1 lane/edge, batch stride 2048
        int nb = (ce - cs + 2047) >> 11;

#define LD2(dst, k, u) { int p = base + 2048 * (k) + 256 * (u); dst = (p < ce) ? adj[p] : DUMMY_E; }
#define GA2(dst, vsrc) dst = hs2[(vsrc) & 0x1FFFFu];
#define AT2(vsrc, val) { unsigned dl = (vsrc) >> 17; \
    atomicAdd(&acc[dl * ACC2S + 0], (val).x); atomicAdd(&acc[dl * ACC2S + 1], (val).y); }
#define LDB2(P, k) LD2(P##0, k, 0) LD2(P##1, k, 1) LD2(P##2, k, 2) LD2(P##3, k, 3) \
                   LD2(P##4, k, 4) LD2(P##5, k, 5) LD2(P##6, k, 6) LD2(P##7, k, 7)
#define GAB2(V, P) GA2(V##0, P##0) GA2(V##1, P##1) GA2(V##2, P##2) GA2(V##3, P##3) \
                   GA2(V##4, P##4) GA2(V##5, P##5) GA2(V##6, P##6) GA2(V##7, P##7)
#define ATB2(P, V) AT2(P##0, V##0) AT2(P##1, V##1) AT2(P##2, V##2) AT2(P##3, V##3) \
                   AT2(P##4, V##4) AT2(P##5, V##5) AT2(P##6, V##6) AT2(P##7, V##7)

        unsigned ia0, ia1, ia2, ia3, ia4, ia5, ia6, ia7;
        unsigned ib0, ib1, ib2, ib3, ib4, ib5, ib6, ib7;
        float2 va0, va1, va2, va3, va4, va5, va6, va7;
        float2 vb0, vb1, vb2, vb3, vb4, vb5, vb6, vb7;

        LDB2(ia, 0)
        int k = 0;
        for (;;) {
            GAB2(va, ia)
            __builtin_amdgcn_sched_barrier(0);
            LDB2(ib, k + 1)
            __builtin_amdgcn_sched_barrier(0);
            ATB2(ia, va)
            ++k; if (k >= nb) break;
            GAB2(vb, ib)
            __builtin_amdgcn_sched_barrier(0);
            LDB2(ia, k + 1)
            __builtin_amdgcn_sched_barrier(0);
            ATB2(ib, vb)
            ++k; if (k >= nb) break;
        }
    }
    __syncthreads();
    float* rb = racc2 + (size_t)b * (BSZ * F_OUT);
    for (int idx = t; idx < BSZ * F_OUT; idx += 256)
        atomicAdd(&rb[idx], acc[(idx >> 1) * ACC2S + (idx & 1)]);
}

// ---------- finalize ----------
__global__ __launch_bounds__(256) void k_fin(const float* __restrict__ racc2,
                                             const float* __restrict__ dinv,
                                             const float* __restrict__ b2,
                                             float* __restrict__ out) {
    int i = blockIdx.x * 256 + threadIdx.x;
    if (i < N_NODES * F_OUT) {
        int n = i >> 1;
        out[i] = fmaf(dinv[n], racc2[i], b2[i & 1]);
    }
}

// ---------- launcher ----------
extern "C" void kernel_launch(void* const* d_in, const int* in_sizes, int n_in,
                              void* d_out, int out_size, void* d_ws, size_t ws_size,
                              hipStream_t stream) {
    const float* x   = (const float*)d_in[0];
    const int*   ei  = (const int*)d_in[1];
    const int*   srcv = ei;
    const int*   dstv = ei + N_EDGES;
    const float* W1  = (const float*)d_in[2];
    const float* b1  = (const float*)d_in[3];
    const float* W2  = (const float*)d_in[4];
    const float* b2  = (const float*)d_in[5];
    float* out = (float*)d_out;

    char* w = (char*)d_ws;
    unsigned* adj        = (unsigned*)w;  w += (size_t)N_EDGES * 4;        // 12.8 MB
    unsigned* blockHist  = (unsigned*)w;  w += (size_t)NB * G * 4;         // 3.2 MB
    unsigned* total      = (unsigned*)w;  w += (size_t)NB * 4;
    unsigned* bucketBase = (unsigned*)w;  w += (size_t)(NB + 1) * 4;
    w = (char*)(((size_t)w + 15) & ~(size_t)15);
    float* dinv  = (float*)w;  w += (size_t)N_NODES * 4;                   // 0.4 MB
    float* hs    = (float*)w;  w += (size_t)NB * BSZ * HIDDEN * 4;         // 6.4 MB
    float* racc  = (float*)w;  w += (size_t)NB * BSZ * HIDDEN * 4;         // 6.4 MB
    float* hs2   = (float*)w;  w += (size_t)NB * BSZ * F_OUT * 4;          // 0.8 MB
    float* racc2 = (float*)w;                                              // 0.8 MB

    k_hist        <<<G, 256, 0, stream>>>(dstv, blockHist);
    k_scan_blocks <<<NB, G, 0, stream>>>(blockHist, total);
    k_scan_buckets<<<1, 1024, 0, stream>>>(total, bucketBase);
    k_scatter     <<<G, 256, 0, stream>>>(srcv, dstv, blockHist, bucketBase, adj);
    k_degree      <<<NB, 256, 0, stream>>>(adj, bucketBase, dinv);
    k_mm1         <<<(NB * BSZ) / MM1_NODES, 256, 0, stream>>>(
                      x, W1, dinv, (float4*)hs, (float4*)racc);
    k_agg1        <<<NB * SPLIT, 256, 0, stream>>>(adj, bucketBase, (const float4*)hs, racc);
    k_mm2         <<<(NB * BSZ + 255) / 256, 256, 0, stream>>>(racc, b1, W2, dinv,
                      (float2*)hs2, (float2*)racc2);
    k_agg2        <<<NB * SPLIT, 256, 0, stream>>>(adj, bucketBase, (const float2*)hs2, racc2);
    k_fin         <<<(N_NODES * F_OUT + 255) / 256, 256, 0, stream>>>(racc2, dinv, b2, out);
}

// Round 5
// 489.649 us; speedup vs baseline: 1.1222x; 1.1222x over previous
//
#include <hip/hip_runtime.h>

#define N_NODES 100000
#define N_EDGES 3200000
#define F_IN    128
#define HIDDEN  16
#define F_OUT   2

#define BSZ     128                  // nodes per bucket
#define NB      782                  // ceil(N_NODES / BSZ)
#define NPAD    (NB * BSZ)           // 100096 padded node rows
#define G       1024                 // edge-partition blocks for hist/scatter
#define EPB     (N_EDGES / G)        // 3125 edges per partition (exact)
#define SPLIT   4                    // blocks per bucket in agg1/agg2
#define DUMMY_E 100000u              // zeroed pad row used for clamped slots
#define ACC1S   17                   // padded LDS row stride (floats)
#define ACC2S   3

typedef float  f32x4 __attribute__((ext_vector_type(4)));
typedef float  f32x2 __attribute__((ext_vector_type(2)));
typedef _Float16 half8 __attribute__((ext_vector_type(8)));
typedef _Float16 half4 __attribute__((ext_vector_type(4)));

// ---------- P1: per-partition bucket histogram ----------
__global__ __launch_bounds__(256) void k_hist(const int* __restrict__ dst,
                                              unsigned* __restrict__ blockHist) {
    __shared__ unsigned hist[NB];
    int t = threadIdx.x, g = blockIdx.x;
    for (int i = t; i < NB; i += 256) hist[i] = 0u;
    __syncthreads();
    int base = g * EPB;
    for (int i = t; i < EPB; i += 256) atomicAdd(&hist[dst[base + i] >> 7], 1u);
    __syncthreads();
    for (int i = t; i < NB; i += 256) blockHist[i * G + g] = hist[i];
}

// ---------- P2: per-bucket exclusive scan over partitions ----------
__global__ __launch_bounds__(G) void k_scan_blocks(unsigned* __restrict__ blockHist,
                                                   unsigned* __restrict__ total) {
    __shared__ unsigned s[G];
    int b = blockIdx.x, t = threadIdx.x;
    unsigned v = blockHist[b * G + t];
    s[t] = v;
    __syncthreads();
    for (int off = 1; off < G; off <<= 1) {
        unsigned xv = (t >= off) ? s[t - off] : 0u;
        __syncthreads();
        s[t] += xv;
        __syncthreads();
    }
    blockHist[b * G + t] = s[t] - v;
    if (t == G - 1) total[b] = s[t];
}

// ---------- P2c: exclusive scan of bucket totals ----------
__global__ __launch_bounds__(1024) void k_scan_buckets(const unsigned* __restrict__ total,
                                                       unsigned* __restrict__ bucketBase) {
    __shared__ unsigned s[1024];
    int t = threadIdx.x;
    unsigned v = (t < NB) ? total[t] : 0u;
    s[t] = v;
    __syncthreads();
    for (int off = 1; off < 1024; off <<= 1) {
        unsigned xv = (t >= off) ? s[t - off] : 0u;
        __syncthreads();
        s[t] += xv;
        __syncthreads();
    }
    if (t < NB) bucketBase[t] = s[t] - v;
    if (t == 1023) bucketBase[NB] = s[t];
}

// ---------- P3: scatter into bucket-sorted adjacency ----------
// entry: (dst & 127) << 17 | src
__global__ __launch_bounds__(256) void k_scatter(const int* __restrict__ src,
                                                 const int* __restrict__ dst,
                                                 const unsigned* __restrict__ blockHist,
                                                 const unsigned* __restrict__ bucketBase,
                                                 unsigned* __restrict__ adj) {
    __shared__ unsigned cur[NB];
    int t = threadIdx.x, g = blockIdx.x;
    for (int i = t; i < NB; i += 256) cur[i] = bucketBase[i] + blockHist[i * G + g];
    __syncthreads();
    int base = g * EPB;
    for (int i = t; i < EPB; i += 256) {
        int s = src[base + i], d = dst[base + i];
        unsigned pos = atomicAdd(&cur[d >> 7], 1u);
        adj[pos] = ((unsigned)(d & 127) << 17) | (unsigned)s;
    }
}

// ---------- P4: degree (incl. self-loop) -> dinv ----------
__global__ __launch_bounds__(256) void k_degree(const unsigned* __restrict__ adj,
                                                const unsigned* __restrict__ bucketBase,
                                                float* __restrict__ dinv) {
    __shared__ unsigned deg[BSZ];
    int b = blockIdx.x, t = threadIdx.x;
    if (t < BSZ) deg[t] = 0u;
    __syncthreads();
    int e0 = (int)bucketBase[b], e1 = (int)bucketBase[b + 1];
    for (int i = e0 + t; i < e1; i += 256) atomicAdd(&deg[adj[i] >> 17], 1u);
    __syncthreads();
    if (t < BSZ) {
        int n = b * BSZ + t;
        if (n < N_NODES) dinv[n] = rsqrtf((float)(deg[t] + 1u));
    }
}

// ---------- layer-1 GEMM: hs(fp16) = (x @ W1) * dinv ; racc(f32) = same ----------
#define MM1_NODES 64
#define SXP 132
__global__ __launch_bounds__(256) void k_mm1(const float* __restrict__ x,
                                             const float* __restrict__ W1,
                                             const float* __restrict__ dinv,
                                             half4* __restrict__ hs,
                                             float4* __restrict__ racc) {
    __shared__ float sW[F_IN * HIDDEN];       // 8 KB
    __shared__ float sX[MM1_NODES * SXP];     // 33 KB
    int t = threadIdx.x;
    for (int i = t; i < F_IN * HIDDEN; i += 256) sW[i] = W1[i];
    int node0 = blockIdx.x * MM1_NODES;
    const float4* xv = (const float4*)(x + (size_t)node0 * F_IN);
    int maxv = (N_NODES - node0) * (F_IN / 4);
    if (maxv < 0) maxv = 0;
    for (int i = t; i < MM1_NODES * (F_IN / 4); i += 256) {
        if (i < maxv) {
            int nl = i >> 5, f4 = i & 31;
            ((float4*)(sX + nl * SXP))[f4] = xv[i];
        }
    }
    __syncthreads();
    int lane4 = t & 3;
    int nl = t >> 2;
    int n = node0 + nl;
    if (n >= NPAD) return;
    if (n >= N_NODES) {                       // zero pad rows incl. DUMMY row
        half4 hz = {(_Float16)0.f, (_Float16)0.f, (_Float16)0.f, (_Float16)0.f};
        float4 z = {0.f, 0.f, 0.f, 0.f};
        hs[(size_t)n * 4 + lane4] = hz;
        racc[(size_t)n * 4 + lane4] = z;
        return;
    }
    const float4* sWv = (const float4*)sW;
    float4 a = {0.f, 0.f, 0.f, 0.f};
    #pragma unroll 8
    for (int f = 0; f < F_IN; ++f) {
        float xval = sX[nl * SXP + f];
        float4 w = sWv[f * 4 + lane4];
        a.x = fmaf(xval, w.x, a.x);
        a.y = fmaf(xval, w.y, a.y);
        a.z = fmaf(xval, w.z, a.z);
        a.w = fmaf(xval, w.w, a.w);
    }
    float dv = dinv[n];
    a.x *= dv; a.y *= dv; a.z *= dv; a.w *= dv;
    half4 h; h[0] = (_Float16)a.x; h[1] = (_Float16)a.y; h[2] = (_Float16)a.z; h[3] = (_Float16)a.w;
    hs[(size_t)n * 4 + lane4] = h;
    racc[(size_t)n * 4 + lane4] = a;          // self-loop init; agg1 accumulates on top
}

// ---------- layer-1 aggregation: asm-forced deep gather pipeline ----------
// 2 lanes/edge, 16B fp16 row-half each; 8 slots in flight per thread.
__global__ __launch_bounds__(256) void k_agg1(const unsigned* __restrict__ adj,
                                              const unsigned* __restrict__ bucketBase,
                                              const char* __restrict__ hs,
                                              float* __restrict__ racc) {
    __shared__ float acc[BSZ * ACC1S];        // 8.7 KB
    int t = threadIdx.x;
    int b = blockIdx.x >> 2, s = blockIdx.x & (SPLIT - 1);
    for (int i = t; i < BSZ * ACC1S; i += 256) acc[i] = 0.f;
    __syncthreads();
    int e0 = (int)bucketBase[b], e1 = (int)bucketBase[b + 1];
    int chunk = (e1 - e0 + SPLIT - 1) >> 2;
    int cs = e0 + s * chunk;
    int ce = cs + chunk; if (ce > e1) ce = e1;
    int le = t & 1;
    unsigned le16 = (unsigned)le * 16u;
    unsigned dummy_off = DUMMY_E * 32u + le16;

    unsigned i0, i1, i2, i3, i4, i5, i6, i7;
    unsigned o0, o1, o2, o3, o4, o5, o6, o7;
    f32x4 v0, v1, v2, v3, v4, v5, v6, v7;

#define IDX1(dst, u_) { int p = bs + 128 * (u_); int pc = (p < ce) ? p : (ce - 1); \
    unsigned ao = (unsigned)pc << 2; \
    asm volatile("global_load_dword %0, %1, %2" : "=v"(dst) : "v"(ao), "s"(adj) : "memory"); }
#define OFF1(o, i_, u_) { int p = bs + 128 * (u_); \
    o = (p < ce) ? (((i_ & 0x1FFFFu) << 5) + le16) : dummy_off; }
#define GLD1(dst, o) asm volatile("global_load_dwordx4 %0, %1, %2" \
    : "=v"(dst) : "v"(o), "s"(hs) : "memory");
#define CMT1(i_, v_) { unsigned dl = i_ >> 17; float* row = &acc[dl * ACC1S + le * 8]; \
    half8 h8; __builtin_memcpy(&h8, &v_, 16); \
    atomicAdd(row + 0, (float)h8[0]); atomicAdd(row + 1, (float)h8[1]); \
    atomicAdd(row + 2, (float)h8[2]); atomicAdd(row + 3, (float)h8[3]); \
    atomicAdd(row + 4, (float)h8[4]); atomicAdd(row + 5, (float)h8[5]); \
    atomicAdd(row + 6, (float)h8[6]); atomicAdd(row + 7, (float)h8[7]); }

    for (int bs = cs + (t >> 1); bs < ce; bs += 1024) {
        IDX1(i0, 0) IDX1(i1, 1) IDX1(i2, 2) IDX1(i3, 3)
        IDX1(i4, 4) IDX1(i5, 5) IDX1(i6, 6) IDX1(i7, 7)
        asm volatile("s_waitcnt vmcnt(0)" ::: "memory");
        __builtin_amdgcn_sched_barrier(0);
        OFF1(o0, i0, 0) OFF1(o1, i1, 1) OFF1(o2, i2, 2) OFF1(o3, i3, 3)
        OFF1(o4, i4, 4) OFF1(o5, i5, 5) OFF1(o6, i6, 6) OFF1(o7, i7, 7)
        GLD1(v0, o0) GLD1(v1, o1) GLD1(v2, o2) GLD1(v3, o3)
        GLD1(v4, o4) GLD1(v5, o5) GLD1(v6, o6) GLD1(v7, o7)
        asm volatile("s_waitcnt vmcnt(0)" ::: "memory");
        __builtin_amdgcn_sched_barrier(0);
        CMT1(i0, v0) CMT1(i1, v1) CMT1(i2, v2) CMT1(i3, v3)
        CMT1(i4, v4) CMT1(i5, v5) CMT1(i6, v6) CMT1(i7, v7)
    }
    __syncthreads();
    float* rb = racc + (size_t)b * (BSZ * HIDDEN);
    for (int idx = t; idx < BSZ * HIDDEN; idx += 256)
        atomicAdd(&rb[idx], acc[(idx >> 4) * ACC1S + (idx & 15)]);
}

// ---------- layer 2: relu/bias + 16->2 GEMM, pre-scaled by dinv ----------
__global__ __launch_bounds__(256) void k_mm2(const float* __restrict__ racc,
                                             const float* __restrict__ b1,
                                             const float* __restrict__ W2,
                                             const float* __restrict__ dinv,
                                             float2* __restrict__ hs2,
                                             float2* __restrict__ racc2) {
    int n = blockIdx.x * 256 + threadIdx.x;
    if (n >= NPAD) return;
    if (n >= N_NODES) {
        float2 z = {0.f, 0.f};
        hs2[n] = z;
        return;
    }
    float dv = dinv[n];
    float a0 = 0.f, a1 = 0.f;
    #pragma unroll
    for (int kk = 0; kk < HIDDEN; ++kk) {
        float v = fmaxf(fmaf(dv, racc[(size_t)n * HIDDEN + kk], b1[kk]), 0.f);
        a0 = fmaf(v, W2[kk * F_OUT + 0], a0);
        a1 = fmaf(v, W2[kk * F_OUT + 1], a1);
    }
    float2 h2; h2.x = a0 * dv; h2.y = a1 * dv;
    hs2[n] = h2;
    racc2[n] = h2;
}

// ---------- layer-2 aggregation: asm pipeline, 1 lane/edge, 8B loads ----------
__global__ __launch_bounds__(256) void k_agg2(const unsigned* __restrict__ adj,
                                              const unsigned* __restrict__ bucketBase,
                                              const char* __restrict__ hs2,
                                              float* __restrict__ racc2) {
    __shared__ float acc[BSZ * ACC2S];
    int t = threadIdx.x;
    int b = blockIdx.x >> 2, s = blockIdx.x & (SPLIT - 1);
    for (int i = t; i < BSZ * ACC2S; i += 256) acc[i] = 0.f;
    __syncthreads();
    int e0 = (int)bucketBase[b], e1 = (int)bucketBase[b + 1];
    int chunk = (e1 - e0 + SPLIT - 1) >> 2;
    int cs = e0 + s * chunk;
    int ce = cs + chunk; if (ce > e1) ce = e1;
    unsigned dummy_off = DUMMY_E * 8u;

    unsigned i0, i1, i2, i3, i4, i5, i6, i7;
    unsigned o0, o1, o2, o3, o4, o5, o6, o7;
    f32x2 v0, v1, v2, v3, v4, v5, v6, v7;

#define IDX2(dst, u_) { int p = bs + 256 * (u_); int pc = (p < ce) ? p : (ce - 1); \
    unsigned ao = (unsigned)pc << 2; \
    asm volatile("global_load_dword %0, %1, %2" : "=v"(dst) : "v"(ao), "s"(adj) : "memory"); }
#define OFF2(o, i_, u_) { int p = bs + 256 * (u_); \
    o = (p < ce) ? ((i_ & 0x1FFFFu) << 3) : dummy_off; }
#define GLD2(dst, o) asm volatile("global_load_dwordx2 %0, %1, %2" \
    : "=v"(dst) : "v"(o), "s"(hs2) : "memory");
#define CMT2(i_, v_) { unsigned dl = i_ >> 17; \
    atomicAdd(&acc[dl * ACC2S + 0], v_[0]); atomicAdd(&acc[dl * ACC2S + 1], v_[1]); }

    for (int bs = cs + t; bs < ce; bs += 2048) {
        IDX2(i0, 0) IDX2(i1, 1) IDX2(i2, 2) IDX2(i3, 3)
        IDX2(i4, 4) IDX2(i5, 5) IDX2(i6, 6) IDX2(i7, 7)
        asm volatile("s_waitcnt vmcnt(0)" ::: "memory");
        __builtin_amdgcn_sched_barrier(0);
        OFF2(o0, i0, 0) OFF2(o1, i1, 1) OFF2(o2, i2, 2) OFF2(o3, i3, 3)
        OFF2(o4, i4, 4) OFF2(o5, i5, 5) OFF2(o6, i6, 6) OFF2(o7, i7, 7)
        GLD2(v0, o0) GLD2(v1, o1) GLD2(v2, o2) GLD2(v3, o3)
        GLD2(v4, o4) GLD2(v5, o5) GLD2(v6, o6) GLD2(v7, o7)
        asm volatile("s_waitcnt vmcnt(0)" ::: "memory");
        __builtin_amdgcn_sched_barrier(0);
        CMT2(i0, v0) CMT2(i1, v1) CMT2(i2, v2) CMT2(i3, v3)
        CMT2(i4, v4) CMT2(i5, v5) CMT2(i6, v6) CMT2(i7, v7)
    }
    __syncthreads();
    float* rb = racc2 + (size_t)b * (BSZ * F_OUT);
    for (int idx = t; idx < BSZ * F_OUT; idx += 256)
        atomicAdd(&rb[idx], acc[(idx >> 1) * ACC2S + (idx & 1)]);
}

// ---------- finalize ----------
__global__ __launch_bounds__(256) void k_fin(const float* __restrict__ racc2,
                                             const float* __restrict__ dinv,
                                             const float* __restrict__ b2,
                                             float* __restrict__ out) {
    int i = blockIdx.x * 256 + threadIdx.x;
    if (i < N_NODES * F_OUT) {
        int n = i >> 1;
        out[i] = fmaf(dinv[n], racc2[i], b2[i & 1]);
    }
}

// ---------- launcher ----------
extern "C" void kernel_launch(void* const* d_in, const int* in_sizes, int n_in,
                              void* d_out, int out_size, void* d_ws, size_t ws_size,
                              hipStream_t stream) {
    const float* x   = (const float*)d_in[0];
    const int*   ei  = (const int*)d_in[1];
    const int*   srcv = ei;
    const int*   dstv = ei + N_EDGES;
    const float* W1  = (const float*)d_in[2];
    const float* b1  = (const float*)d_in[3];
    const float* W2  = (const float*)d_in[4];
    const float* b2  = (const float*)d_in[5];
    float* out = (float*)d_out;

    char* w = (char*)d_ws;
    unsigned* adj        = (unsigned*)w;  w += (size_t)N_EDGES * 4;        // 12.8 MB
    unsigned* blockHist  = (unsigned*)w;  w += (size_t)NB * G * 4;         // 3.2 MB
    unsigned* total      = (unsigned*)w;  w += (size_t)NB * 4;
    unsigned* bucketBase = (unsigned*)w;  w += (size_t)(NB + 1) * 4;
    w = (char*)(((size_t)w + 15) & ~(size_t)15);
    float* dinv  = (float*)w;  w += (size_t)N_NODES * 4;                   // 0.4 MB
    char*  hs    = w;          w += (size_t)NPAD * HIDDEN * 2;             // 3.2 MB fp16
    float* racc  = (float*)w;  w += (size_t)NPAD * HIDDEN * 4;             // 6.4 MB
    float* hs2   = (float*)w;  w += (size_t)NPAD * F_OUT * 4;              // 0.8 MB
    float* racc2 = (float*)w;                                              // 0.8 MB

    k_hist        <<<G, 256, 0, stream>>>(dstv, blockHist);
    k_scan_blocks <<<NB, G, 0, stream>>>(blockHist, total);
    k_scan_buckets<<<1, 1024, 0, stream>>>(total, bucketBase);
    k_scatter     <<<G, 256, 0, stream>>>(srcv, dstv, blockHist, bucketBase, adj);
    k_degree      <<<NB, 256, 0, stream>>>(adj, bucketBase, dinv);
    k_mm1         <<<NPAD / MM1_NODES, 256, 0, stream>>>(
                      x, W1, dinv, (half4*)hs, (float4*)racc);
    k_agg1        <<<NB * SPLIT, 256, 0, stream>>>(adj, bucketBase, hs, racc);
    k_mm2         <<<(NPAD + 255) / 256, 256, 0, stream>>>(racc, b1, W2, dinv,
                      (float2*)hs2, (float2*)racc2);
    k_agg2        <<<NB * SPLIT, 256, 0, stream>>>(adj, bucketBase, (const char*)hs2, racc2);
    k_fin         <<<(N_NODES * F_OUT + 255) / 256, 256, 0, stream>>>(racc2, dinv, b2, out);
}

// Round 6
// 150.764 us; speedup vs baseline: 3.6447x; 3.2478x over previous
//
#include <hip/hip_runtime.h>

#define N_NODES 100000
#define N_EDGES 3200000
#define F_IN    128
#define HIDDEN  16
#define F_OUT   2

#define BSZ     128                  // nodes per bucket
#define NB      782                  // ceil(N_NODES / BSZ)
#define NPAD    (NB * BSZ)           // 100096 padded node rows
#define G       512                  // edge-partition blocks for hist/scatter
#define EPB     (N_EDGES / G)        // 6250 edges per partition (exact)
#define DUMMY_E 100000u              // zeroed pad row used for clamped slots

typedef float  f32x4 __attribute__((ext_vector_type(4)));
typedef float  f32x2 __attribute__((ext_vector_type(2)));
typedef _Float16 half8 __attribute__((ext_vector_type(8)));
typedef _Float16 half4 __attribute__((ext_vector_type(4)));

// ---------- P1: per-partition bucket histogram ----------
__global__ __launch_bounds__(256) void k_hist(const int* __restrict__ dst,
                                              unsigned* __restrict__ blockHist) {
    __shared__ unsigned hist[NB];
    int t = threadIdx.x, g = blockIdx.x;
    for (int i = t; i < NB; i += 256) hist[i] = 0u;
    __syncthreads();
    int base = g * EPB;
    for (int i = t; i < EPB; i += 256) atomicAdd(&hist[dst[base + i] >> 7], 1u);
    __syncthreads();
    for (int i = t; i < NB; i += 256) blockHist[i * G + g] = hist[i];
}

// ---------- P2: per-bucket exclusive scan over partitions ----------
__global__ __launch_bounds__(G) void k_scan_blocks(unsigned* __restrict__ blockHist,
                                                   unsigned* __restrict__ total) {
    __shared__ unsigned s[G];
    int b = blockIdx.x, t = threadIdx.x;
    unsigned v = blockHist[b * G + t];
    s[t] = v;
    __syncthreads();
    for (int off = 1; off < G; off <<= 1) {
        unsigned xv = (t >= off) ? s[t - off] : 0u;
        __syncthreads();
        s[t] += xv;
        __syncthreads();
    }
    blockHist[b * G + t] = s[t] - v;
    if (t == G - 1) total[b] = s[t];
}

// ---------- P2c: exclusive scan of bucket totals ----------
__global__ __launch_bounds__(1024) void k_scan_buckets(const unsigned* __restrict__ total,
                                                       unsigned* __restrict__ bucketBase,
                                                       int* __restrict__ rowstart) {
    __shared__ unsigned s[1024];
    int t = threadIdx.x;
    unsigned v = (t < NB) ? total[t] : 0u;
    s[t] = v;
    __syncthreads();
    for (int off = 1; off < 1024; off <<= 1) {
        unsigned xv = (t >= off) ? s[t - off] : 0u;
        __syncthreads();
        s[t] += xv;
        __syncthreads();
    }
    if (t < NB) bucketBase[t] = s[t] - v;
    if (t == 1023) {
        bucketBase[NB] = s[t];                 // == N_EDGES
        rowstart[N_NODES] = (int)s[t];
    }
}

// ---------- P3: scatter into bucket-sorted adjacency ----------
// entry: (dst & 127) << 17 | src
__global__ __launch_bounds__(256) void k_scatter(const int* __restrict__ src,
                                                 const int* __restrict__ dst,
                                                 const unsigned* __restrict__ blockHist,
                                                 const unsigned* __restrict__ bucketBase,
                                                 unsigned* __restrict__ adj) {
    __shared__ unsigned cur[NB];
    int t = threadIdx.x, g = blockIdx.x;
    for (int i = t; i < NB; i += 256) cur[i] = bucketBase[i] + blockHist[i * G + g];
    __syncthreads();
    int base = g * EPB;
    for (int i = t; i < EPB; i += 256) {
        int s = src[base + i], d = dst[base + i];
        unsigned pos = atomicAdd(&cur[d >> 7], 1u);
        adj[pos] = ((unsigned)(d & 127) << 17) | (unsigned)s;
    }
}

// ---------- P4: in-bucket counting sort -> CSR (adj2 = src only), rowstart, dinv ----------
__global__ __launch_bounds__(256) void k_sortbucket(const unsigned* __restrict__ adj,
                                                    const unsigned* __restrict__ bucketBase,
                                                    unsigned* __restrict__ adj2,
                                                    int* __restrict__ rowstart,
                                                    float* __restrict__ dinv) {
    __shared__ unsigned hist[BSZ];
    __shared__ unsigned sc[BSZ];
    __shared__ unsigned cur[BSZ];
    int b = blockIdx.x, t = threadIdx.x;
    if (t < BSZ) hist[t] = 0u;
    __syncthreads();
    int e0 = (int)bucketBase[b], e1 = (int)bucketBase[b + 1];
    for (int i = e0 + t; i < e1; i += 256) atomicAdd(&hist[adj[i] >> 17], 1u);
    __syncthreads();
    if (t < BSZ) sc[t] = hist[t];
    __syncthreads();
    for (int off = 1; off < BSZ; off <<= 1) {
        unsigned a = 0;
        if (t < BSZ && t >= off) a = sc[t - off];
        __syncthreads();
        if (t < BSZ) sc[t] += a;
        __syncthreads();
    }
    if (t < BSZ) {
        unsigned excl = sc[t] - hist[t];
        cur[t] = (unsigned)e0 + excl;
        int node = b * BSZ + t;
        if (node < N_NODES) {
            rowstart[node] = e0 + (int)excl;
            dinv[node] = rsqrtf((float)(hist[t] + 1u));
        }
    }
    __syncthreads();
    for (int i = e0 + t; i < e1; i += 256) {
        unsigned v = adj[i];
        unsigned pos = atomicAdd(&cur[v >> 17], 1u);
        adj2[pos] = v & 0x1FFFFu;
    }
}

// ---------- layer-1 GEMM: hs(fp16) = (x @ W1) * dinv ----------
#define MM1_NODES 64
#define SXP 132
__global__ __launch_bounds__(256) void k_mm1(const float* __restrict__ x,
                                             const float* __restrict__ W1,
                                             const float* __restrict__ dinv,
                                             half4* __restrict__ hs) {
    __shared__ float sW[F_IN * HIDDEN];       // 8 KB
    __shared__ float sX[MM1_NODES * SXP];     // 33 KB
    int t = threadIdx.x;
    for (int i = t; i < F_IN * HIDDEN; i += 256) sW[i] = W1[i];
    int node0 = blockIdx.x * MM1_NODES;
    const float4* xv = (const float4*)(x + (size_t)node0 * F_IN);
    int maxv = (N_NODES - node0) * (F_IN / 4);
    if (maxv < 0) maxv = 0;
    for (int i = t; i < MM1_NODES * (F_IN / 4); i += 256) {
        if (i < maxv) {
            int nl = i >> 5, f4 = i & 31;
            ((float4*)(sX + nl * SXP))[f4] = xv[i];
        }
    }
    __syncthreads();
    int lane4 = t & 3;
    int nl = t >> 2;
    int n = node0 + nl;
    if (n >= NPAD) return;
    if (n >= N_NODES) {                       // zero pad rows incl. DUMMY row
        half4 hz = {(_Float16)0.f, (_Float16)0.f, (_Float16)0.f, (_Float16)0.f};
        hs[(size_t)n * 4 + lane4] = hz;
        return;
    }
    const float4* sWv = (const float4*)sW;
    float4 a = {0.f, 0.f, 0.f, 0.f};
    #pragma unroll 8
    for (int f = 0; f < F_IN; ++f) {
        float xval = sX[nl * SXP + f];
        float4 w = sWv[f * 4 + lane4];
        a.x = fmaf(xval, w.x, a.x);
        a.y = fmaf(xval, w.y, a.y);
        a.z = fmaf(xval, w.z, a.z);
        a.w = fmaf(xval, w.w, a.w);
    }
    float dv = dinv[n];
    half4 h; h[0] = (_Float16)(a.x * dv); h[1] = (_Float16)(a.y * dv);
    h[2] = (_Float16)(a.z * dv); h[3] = (_Float16)(a.w * dv);
    hs[(size_t)n * 4 + lane4] = h;
}

// ---------- layer-1 aggregation: CSR segment scan, register accumulate, no atomics ----------
// 2 lanes per node; each lane owns 8 fp16 channels (16B of the 32B row).
__global__ __launch_bounds__(256) void k_agg1(const unsigned* __restrict__ adj2,
                                              const int* __restrict__ rowstart,
                                              const char* __restrict__ hs,
                                              const float* __restrict__ dinv,
                                              float* __restrict__ out1) {
    int g = blockIdx.x * 256 + threadIdx.x;
    int node = g >> 1, le = g & 1;
    if (node >= N_NODES) return;
    int rs = rowstart[node], re = rowstart[node + 1];
    unsigned le16 = (unsigned)le * 16u;
    unsigned dummy_off = DUMMY_E * 32u + le16;

    float a0 = 0.f, a1 = 0.f, a2 = 0.f, a3 = 0.f, a4 = 0.f, a5 = 0.f, a6 = 0.f, a7 = 0.f;
    f32x4 w0, w1, w2, w3, w4, w5, w6, w7;

#define GL1(dst, o) asm volatile("global_load_dwordx4 %0, %1, %2" \
    : "=v"(dst) : "v"(o), "s"(hs) : "memory");
#define AC1(w_) { half8 h8; __builtin_memcpy(&h8, &w_, 16); \
    a0 += (float)h8[0]; a1 += (float)h8[1]; a2 += (float)h8[2]; a3 += (float)h8[3]; \
    a4 += (float)h8[4]; a5 += (float)h8[5]; a6 += (float)h8[6]; a7 += (float)h8[7]; }

    for (int bs = rs; bs < re; bs += 8) {
        const unsigned* ap = adj2 + bs;        // adj2 padded by 8 -> safe reads
        unsigned j0 = ap[0], j1 = ap[1], j2 = ap[2], j3 = ap[3];
        unsigned j4 = ap[4], j5 = ap[5], j6 = ap[6], j7 = ap[7];
        unsigned o0 = (bs + 0 < re) ? (j0 << 5) + le16 : dummy_off;
        unsigned o1 = (bs + 1 < re) ? (j1 << 5) + le16 : dummy_off;
        unsigned o2 = (bs + 2 < re) ? (j2 << 5) + le16 : dummy_off;
        unsigned o3 = (bs + 3 < re) ? (j3 << 5) + le16 : dummy_off;
        unsigned o4 = (bs + 4 < re) ? (j4 << 5) + le16 : dummy_off;
        unsigned o5 = (bs + 5 < re) ? (j5 << 5) + le16 : dummy_off;
        unsigned o6 = (bs + 6 < re) ? (j6 << 5) + le16 : dummy_off;
        unsigned o7 = (bs + 7 < re) ? (j7 << 5) + le16 : dummy_off;
        GL1(w0, o0) GL1(w1, o1) GL1(w2, o2) GL1(w3, o3)
        GL1(w4, o4) GL1(w5, o5) GL1(w6, o6) GL1(w7, o7)
        asm volatile("s_waitcnt vmcnt(0)" ::: "memory");
        __builtin_amdgcn_sched_barrier(0);
        AC1(w0) AC1(w1) AC1(w2) AC1(w3) AC1(w4) AC1(w5) AC1(w6) AC1(w7)
    }
    // self term + scale + direct store
    const _Float16* selfrow = (const _Float16*)(hs + (size_t)node * 32 + le16);
    float dv = dinv[node];
    float4 q0, q1;
    q0.x = dv * (a0 + (float)selfrow[0]); q0.y = dv * (a1 + (float)selfrow[1]);
    q0.z = dv * (a2 + (float)selfrow[2]); q0.w = dv * (a3 + (float)selfrow[3]);
    q1.x = dv * (a4 + (float)selfrow[4]); q1.y = dv * (a5 + (float)selfrow[5]);
    q1.z = dv * (a6 + (float)selfrow[6]); q1.w = dv * (a7 + (float)selfrow[7]);
    float* op = out1 + (size_t)node * HIDDEN + le * 8;
    *(float4*)(op + 0) = q0;
    *(float4*)(op + 4) = q1;
}

// ---------- layer 2: relu/bias + 16->2 GEMM, pre-scaled by dinv ----------
__global__ __launch_bounds__(256) void k_mm2(const float* __restrict__ out1,
                                             const float* __restrict__ b1,
                                             const float* __restrict__ W2,
                                             const float* __restrict__ dinv,
                                             float2* __restrict__ hs2) {
    int n = blockIdx.x * 256 + threadIdx.x;
    if (n >= NPAD) return;
    if (n >= N_NODES) {                        // zero pad rows incl. DUMMY
        float2 z = {0.f, 0.f};
        hs2[n] = z;
        return;
    }
    float a0 = 0.f, a1 = 0.f;
    #pragma unroll
    for (int kk = 0; kk < HIDDEN; ++kk) {
        float v = fmaxf(out1[(size_t)n * HIDDEN + kk] + b1[kk], 0.f);  // out1 already has dinv_d
        a0 = fmaf(v, W2[kk * F_OUT + 0], a0);
        a1 = fmaf(v, W2[kk * F_OUT + 1], a1);
    }
    float dv = dinv[n];
    float2 h2; h2.x = a0 * dv; h2.y = a1 * dv;
    hs2[n] = h2;
}

// ---------- layer-2 aggregation + finalize: 1 lane/node, register acc ----------
__global__ __launch_bounds__(256) void k_agg2(const unsigned* __restrict__ adj2,
                                              const int* __restrict__ rowstart,
                                              const char* __restrict__ hs2,
                                              const float* __restrict__ dinv,
                                              const float* __restrict__ b2,
                                              float2* __restrict__ out) {
    int node = blockIdx.x * 256 + threadIdx.x;
    if (node >= N_NODES) return;
    int rs = rowstart[node], re = rowstart[node + 1];
    unsigned dummy_off = DUMMY_E * 8u;

    float a0 = 0.f, a1 = 0.f;
    f32x2 w0, w1, w2, w3, w4, w5, w6, w7;

#define GL2(dst, o) asm volatile("global_load_dwordx2 %0, %1, %2" \
    : "=v"(dst) : "v"(o), "s"(hs2) : "memory");

    for (int bs = rs; bs < re; bs += 8) {
        const unsigned* ap = adj2 + bs;
        unsigned j0 = ap[0], j1 = ap[1], j2 = ap[2], j3 = ap[3];
        unsigned j4 = ap[4], j5 = ap[5], j6 = ap[6], j7 = ap[7];
        unsigned o0 = (bs + 0 < re) ? (j0 << 3) : dummy_off;
        unsigned o1 = (bs + 1 < re) ? (j1 << 3) : dummy_off;
        unsigned o2 = (bs + 2 < re) ? (j2 << 3) : dummy_off;
        unsigned o3 = (bs + 3 < re) ? (j3 << 3) : dummy_off;
        unsigned o4 = (bs + 4 < re) ? (j4 << 3) : dummy_off;
        unsigned o5 = (bs + 5 < re) ? (j5 << 3) : dummy_off;
        unsigned o6 = (bs + 6 < re) ? (j6 << 3) : dummy_off;
        unsigned o7 = (bs + 7 < re) ? (j7 << 3) : dummy_off;
        GL2(w0, o0) GL2(w1, o1) GL2(w2, o2) GL2(w3, o3)
        GL2(w4, o4) GL2(w5, o5) GL2(w6, o6) GL2(w7, o7)
        asm volatile("s_waitcnt vmcnt(0)" ::: "memory");
        __builtin_amdgcn_sched_barrier(0);
        a0 += w0[0] + w1[0] + w2[0] + w3[0] + w4[0] + w5[0] + w6[0] + w7[0];
        a1 += w0[1] + w1[1] + w2[1] + w3[1] + w4[1] + w5[1] + w6[1] + w7[1];
    }
    const float2* h2p = (const float2*)hs2;
    float2 selfv = h2p[node];
    float dv = dinv[node];
    float2 r;
    r.x = fmaf(dv, a0 + selfv.x, b2[0]);
    r.y = fmaf(dv, a1 + selfv.y, b2[1]);
    out[node] = r;
}

// ---------- launcher ----------
extern "C" void kernel_launch(void* const* d_in, const int* in_sizes, int n_in,
                              void* d_out, int out_size, void* d_ws, size_t ws_size,
                              hipStream_t stream) {
    const float* x   = (const float*)d_in[0];
    const int*   ei  = (const int*)d_in[1];
    const int*   srcv = ei;
    const int*   dstv = ei + N_EDGES;
    const float* W1  = (const float*)d_in[2];
    const float* b1  = (const float*)d_in[3];
    const float* W2  = (const float*)d_in[4];
    const float* b2  = (const float*)d_in[5];
    float* out = (float*)d_out;

    char* w = (char*)d_ws;
    unsigned* adj        = (unsigned*)w;  w += (size_t)N_EDGES * 4;        // 12.8 MB (dead after sortbucket)
    float*    out1       = (float*)adj;                                    // alias: used only after sortbucket
    unsigned* adj2       = (unsigned*)w;  w += (size_t)(N_EDGES + 8) * 4;  // 12.8 MB + pad
    unsigned* blockHist  = (unsigned*)w;  w += (size_t)NB * G * 4;         // 1.6 MB
    unsigned* total      = (unsigned*)w;  w += (size_t)NB * 4;
    unsigned* bucketBase = (unsigned*)w;  w += (size_t)(NB + 1) * 4;
    int*      rowstart   = (int*)w;       w += (size_t)(N_NODES + 1) * 4;  // 0.4 MB
    w = (char*)(((size_t)w + 15) & ~(size_t)15);
    float* dinv  = (float*)w;  w += (size_t)N_NODES * 4;                   // 0.4 MB
    char*  hs    = w;          w += (size_t)NPAD * HIDDEN * 2;             // 3.2 MB fp16
    float* hs2   = (float*)w;                                              // 0.8 MB

    k_hist        <<<G, 256, 0, stream>>>(dstv, blockHist);
    k_scan_blocks <<<NB, G, 0, stream>>>(blockHist, total);
    k_scan_buckets<<<1, 1024, 0, stream>>>(total, bucketBase, rowstart);
    k_scatter     <<<G, 256, 0, stream>>>(srcv, dstv, blockHist, bucketBase, adj);
    k_sortbucket  <<<NB, 256, 0, stream>>>(adj, bucketBase, adj2, rowstart, dinv);
    k_mm1         <<<NPAD / MM1_NODES, 256, 0, stream>>>(x, W1, dinv, (half4*)hs);
    k_agg1        <<<(2 * NPAD) / 256, 256, 0, stream>>>(adj2, rowstart, hs, dinv, out1);
    k_mm2         <<<(NPAD + 255) / 256, 256, 0, stream>>>(out1, b1, W2, dinv, (float2*)hs2);
    k_agg2        <<<(NPAD + 255) / 256, 256, 0, stream>>>(adj2, rowstart, (const char*)hs2,
                                                           dinv, b2, (float2*)out);
}

// Round 7
// 138.254 us; speedup vs baseline: 3.9745x; 1.0905x over previous
//
#include <hip/hip_runtime.h>

#define N_NODES 100000
#define N_EDGES 3200000
#define F_IN    128
#define HIDDEN  16
#define F_OUT   2

#define BSZ     128                  // nodes per bucket
#define NB      782                  // ceil(N_NODES / BSZ)
#define NPAD    (NB * BSZ)           // 100096 padded node rows
#define G       512                  // edge-partition blocks for hist/scatter
#define EPB     (N_EDGES / G)        // 6250 edges per partition (exact)
#define DUMMY_E 100000u              // zeroed pad row used for clamped slots

typedef float  f32x4 __attribute__((ext_vector_type(4)));
typedef float  f32x2 __attribute__((ext_vector_type(2)));
typedef _Float16 half8 __attribute__((ext_vector_type(8)));
typedef _Float16 half4 __attribute__((ext_vector_type(4)));

// ---------- P1: per-partition bucket histogram ----------
__global__ __launch_bounds__(256) void k_hist(const int* __restrict__ dst,
                                              unsigned* __restrict__ blockHist) {
    __shared__ unsigned hist[NB];
    int t = threadIdx.x, g = blockIdx.x;
    for (int i = t; i < NB; i += 256) hist[i] = 0u;
    __syncthreads();
    int base = g * EPB;
    for (int i = t; i < EPB; i += 256) atomicAdd(&hist[dst[base + i] >> 7], 1u);
    __syncthreads();
    for (int i = t; i < NB; i += 256) blockHist[i * G + g] = hist[i];
}

// ---------- P2: per-bucket exclusive scan over partitions ----------
__global__ __launch_bounds__(G) void k_scan_blocks(unsigned* __restrict__ blockHist,
                                                   unsigned* __restrict__ total) {
    __shared__ unsigned s[G];
    int b = blockIdx.x, t = threadIdx.x;
    unsigned v = blockHist[b * G + t];
    s[t] = v;
    __syncthreads();
    for (int off = 1; off < G; off <<= 1) {
        unsigned xv = (t >= off) ? s[t - off] : 0u;
        __syncthreads();
        s[t] += xv;
        __syncthreads();
    }
    blockHist[b * G + t] = s[t] - v;
    if (t == G - 1) total[b] = s[t];
}

// ---------- P2c: exclusive scan of bucket totals ----------
__global__ __launch_bounds__(1024) void k_scan_buckets(const unsigned* __restrict__ total,
                                                       unsigned* __restrict__ bucketBase,
                                                       int* __restrict__ rowstart) {
    __shared__ unsigned s[1024];
    int t = threadIdx.x;
    unsigned v = (t < NB) ? total[t] : 0u;
    s[t] = v;
    __syncthreads();
    for (int off = 1; off < 1024; off <<= 1) {
        unsigned xv = (t >= off) ? s[t - off] : 0u;
        __syncthreads();
        s[t] += xv;
        __syncthreads();
    }
    if (t < NB) bucketBase[t] = s[t] - v;
    if (t == 1023) {
        bucketBase[NB] = s[t];                 // == N_EDGES
        rowstart[N_NODES] = (int)s[t];
    }
}

// ---------- P3: LDS counting-sort scatter -> bucket-sorted adjacency ----------
// Stage all EPB entries in LDS ordered by bucket, then write grouped runs.
__global__ __launch_bounds__(256) void k_scatter(const int* __restrict__ src,
                                                 const int* __restrict__ dst,
                                                 const unsigned* __restrict__ blockHist,
                                                 const unsigned* __restrict__ bucketBase,
                                                 unsigned* __restrict__ adj) {
    __shared__ unsigned stage[EPB];            // 25.0 KB packed entries, bucket-ordered
    __shared__ unsigned short stage_b[EPB];    // 12.5 KB bucket id per staged entry
    __shared__ unsigned hist[NB];              // counts -> cursor
    __shared__ unsigned lstart[NB];            // local exclusive scan
    __shared__ unsigned gbase[NB];             // global dest base for this block
    __shared__ unsigned ssum[256];
    int t = threadIdx.x, g = blockIdx.x;
    for (int i = t; i < NB; i += 256) {
        hist[i] = 0u;
        gbase[i] = bucketBase[i] + blockHist[i * G + g];   // blockHist already scanned
    }
    __syncthreads();
    int base = g * EPB;
    const int* srcg = src + base;
    const int* dstg = dst + base;
    // phase 1: local histogram
    for (int i = t; i < EPB; i += 256) atomicAdd(&hist[(unsigned)dstg[i] >> 7], 1u);
    __syncthreads();
    // phase 2: exclusive scan of hist -> lstart; hist becomes cursor
    int i0 = t * 4;
    unsigned v0 = (i0 + 0 < NB) ? hist[i0 + 0] : 0u;
    unsigned v1 = (i0 + 1 < NB) ? hist[i0 + 1] : 0u;
    unsigned v2 = (i0 + 2 < NB) ? hist[i0 + 2] : 0u;
    unsigned v3 = (i0 + 3 < NB) ? hist[i0 + 3] : 0u;
    unsigned my = v0 + v1 + v2 + v3;
    ssum[t] = my;
    __syncthreads();
    for (int off = 1; off < 256; off <<= 1) {
        unsigned xv = (t >= off) ? ssum[t - off] : 0u;
        __syncthreads();
        ssum[t] += xv;
        __syncthreads();
    }
    unsigned e0 = ssum[t] - my;
    __syncthreads();                            // all reads of hist done
    unsigned e1 = e0 + v0, e2 = e1 + v1, e3 = e2 + v2;
    if (i0 + 0 < NB) { lstart[i0 + 0] = e0; hist[i0 + 0] = e0; }
    if (i0 + 1 < NB) { lstart[i0 + 1] = e1; hist[i0 + 1] = e1; }
    if (i0 + 2 < NB) { lstart[i0 + 2] = e2; hist[i0 + 2] = e2; }
    if (i0 + 3 < NB) { lstart[i0 + 3] = e3; hist[i0 + 3] = e3; }
    __syncthreads();
    // phase 3: stage entries bucket-ordered in LDS
    for (int i = t; i < EPB; i += 256) {
        int s = srcg[i], d = dstg[i];
        unsigned bkt = (unsigned)d >> 7;
        unsigned pos = atomicAdd(&hist[bkt], 1u);
        stage[pos] = ((unsigned)(d & 127) << 17) | (unsigned)s;
        stage_b[pos] = (unsigned short)bkt;
    }
    __syncthreads();
    // phase 4: grouped global writes (ascending runs per bucket)
    for (int j = t; j < EPB; j += 256) {
        unsigned bkt = stage_b[j];
        adj[gbase[bkt] + (j - lstart[bkt])] = stage[j];
    }
}

// ---------- P4: in-bucket counting sort -> CSR (adj2 = src only), rowstart, dinv ----------
__global__ __launch_bounds__(256) void k_sortbucket(const unsigned* __restrict__ adj,
                                                    const unsigned* __restrict__ bucketBase,
                                                    unsigned* __restrict__ adj2,
                                                    int* __restrict__ rowstart,
                                                    float* __restrict__ dinv) {
    __shared__ unsigned hist[BSZ];
    __shared__ unsigned sc[BSZ];
    __shared__ unsigned cur[BSZ];
    int b = blockIdx.x, t = threadIdx.x;
    if (t < BSZ) hist[t] = 0u;
    __syncthreads();
    int e0 = (int)bucketBase[b], e1 = (int)bucketBase[b + 1];
    for (int i = e0 + t; i < e1; i += 256) atomicAdd(&hist[adj[i] >> 17], 1u);
    __syncthreads();
    if (t < BSZ) sc[t] = hist[t];
    __syncthreads();
    for (int off = 1; off < BSZ; off <<= 1) {
        unsigned a = 0;
        if (t < BSZ && t >= off) a = sc[t - off];
        __syncthreads();
        if (t < BSZ) sc[t] += a;
        __syncthreads();
    }
    if (t < BSZ) {
        unsigned excl = sc[t] - hist[t];
        cur[t] = (unsigned)e0 + excl;
        int node = b * BSZ + t;
        if (node < N_NODES) {
            rowstart[node] = e0 + (int)excl;
            dinv[node] = rsqrtf((float)(hist[t] + 1u));
        }
    }
    __syncthreads();
    for (int i = e0 + t; i < e1; i += 256) {
        unsigned v = adj[i];
        unsigned pos = atomicAdd(&cur[v >> 17], 1u);
        adj2[pos] = v & 0x1FFFFu;
    }
}

// ---------- layer-1 GEMM: hs(fp16) = (x @ W1) * dinv ----------
#define MM1_NODES 64
#define SXP 132
__global__ __launch_bounds__(256) void k_mm1(const float* __restrict__ x,
                                             const float* __restrict__ W1,
                                             const float* __restrict__ dinv,
                                             half4* __restrict__ hs) {
    __shared__ float sW[F_IN * HIDDEN];       // 8 KB
    __shared__ float sX[MM1_NODES * SXP];     // 33 KB
    int t = threadIdx.x;
    for (int i = t; i < F_IN * HIDDEN; i += 256) sW[i] = W1[i];
    int node0 = blockIdx.x * MM1_NODES;
    const float4* xv = (const float4*)(x + (size_t)node0 * F_IN);
    int maxv = (N_NODES - node0) * (F_IN / 4);
    if (maxv < 0) maxv = 0;
    for (int i = t; i < MM1_NODES * (F_IN / 4); i += 256) {
        if (i < maxv) {
            int nl = i >> 5, f4 = i & 31;
            ((float4*)(sX + nl * SXP))[f4] = xv[i];
        }
    }
    __syncthreads();
    int lane4 = t & 3;
    int nl = t >> 2;
    int n = node0 + nl;
    if (n >= NPAD) return;
    if (n >= N_NODES) {                       // zero pad rows incl. DUMMY row
        half4 hz = {(_Float16)0.f, (_Float16)0.f, (_Float16)0.f, (_Float16)0.f};
        hs[(size_t)n * 4 + lane4] = hz;
        return;
    }
    const float4* sWv = (const float4*)sW;
    float4 a = {0.f, 0.f, 0.f, 0.f};
    #pragma unroll 8
    for (int f = 0; f < F_IN; ++f) {
        float xval = sX[nl * SXP + f];
        float4 w = sWv[f * 4 + lane4];
        a.x = fmaf(xval, w.x, a.x);
        a.y = fmaf(xval, w.y, a.y);
        a.z = fmaf(xval, w.z, a.z);
        a.w = fmaf(xval, w.w, a.w);
    }
    float dv = dinv[n];
    half4 h; h[0] = (_Float16)(a.x * dv); h[1] = (_Float16)(a.y * dv);
    h[2] = (_Float16)(a.z * dv); h[3] = (_Float16)(a.w * dv);
    hs[(size_t)n * 4 + lane4] = h;
}

// ---------- layer-1 aggregation: CSR segment scan, register accumulate, no atomics ----------
// 2 lanes per node; each lane owns 8 fp16 channels (16B of the 32B row).
__global__ __launch_bounds__(256) void k_agg1(const unsigned* __restrict__ adj2,
                                              const int* __restrict__ rowstart,
                                              const char* __restrict__ hs,
                                              const float* __restrict__ dinv,
                                              float* __restrict__ out1) {
    int g = blockIdx.x * 256 + threadIdx.x;
    int node = g >> 1, le = g & 1;
    if (node >= N_NODES) return;
    int rs = rowstart[node], re = rowstart[node + 1];
    unsigned le16 = (unsigned)le * 16u;
    unsigned dummy_off = DUMMY_E * 32u + le16;

    float a0 = 0.f, a1 = 0.f, a2 = 0.f, a3 = 0.f, a4 = 0.f, a5 = 0.f, a6 = 0.f, a7 = 0.f;
    f32x4 w0, w1, w2, w3, w4, w5, w6, w7;

#define GL1(dst, o) asm volatile("global_load_dwordx4 %0, %1, %2" \
    : "=v"(dst) : "v"(o), "s"(hs) : "memory");
#define AC1(w_) { half8 h8; __builtin_memcpy(&h8, &w_, 16); \
    a0 += (float)h8[0]; a1 += (float)h8[1]; a2 += (float)h8[2]; a3 += (float)h8[3]; \
    a4 += (float)h8[4]; a5 += (float)h8[5]; a6 += (float)h8[6]; a7 += (float)h8[7]; }

    for (int bs = rs; bs < re; bs += 8) {
        const unsigned* ap = adj2 + bs;        // adj2 padded by 8 -> safe reads
        unsigned j0 = ap[0], j1 = ap[1], j2 = ap[2], j3 = ap[3];
        unsigned j4 = ap[4], j5 = ap[5], j6 = ap[6], j7 = ap[7];
        unsigned o0 = (bs + 0 < re) ? (j0 << 5) + le16 : dummy_off;
        unsigned o1 = (bs + 1 < re) ? (j1 << 5) + le16 : dummy_off;
        unsigned o2 = (bs + 2 < re) ? (j2 << 5) + le16 : dummy_off;
        unsigned o3 = (bs + 3 < re) ? (j3 << 5) + le16 : dummy_off;
        unsigned o4 = (bs + 4 < re) ? (j4 << 5) + le16 : dummy_off;
        unsigned o5 = (bs + 5 < re) ? (j5 << 5) + le16 : dummy_off;
        unsigned o6 = (bs + 6 < re) ? (j6 << 5) + le16 : dummy_off;
        unsigned o7 = (bs + 7 < re) ? (j7 << 5) + le16 : dummy_off;
        GL1(w0, o0) GL1(w1, o1) GL1(w2, o2) GL1(w3, o3)
        GL1(w4, o4) GL1(w5, o5) GL1(w6, o6) GL1(w7, o7)
        asm volatile("s_waitcnt vmcnt(0)" ::: "memory");
        __builtin_amdgcn_sched_barrier(0);
        AC1(w0) AC1(w1) AC1(w2) AC1(w3) AC1(w4) AC1(w5) AC1(w6) AC1(w7)
    }
    // self term + scale + direct store
    const _Float16* selfrow = (const _Float16*)(hs + (size_t)node * 32 + le16);
    float dv = dinv[node];
    float4 q0, q1;
    q0.x = dv * (a0 + (float)selfrow[0]); q0.y = dv * (a1 + (float)selfrow[1]);
    q0.z = dv * (a2 + (float)selfrow[2]); q0.w = dv * (a3 + (float)selfrow[3]);
    q1.x = dv * (a4 + (float)selfrow[4]); q1.y = dv * (a5 + (float)selfrow[5]);
    q1.z = dv * (a6 + (float)selfrow[6]); q1.w = dv * (a7 + (float)selfrow[7]);
    float* op = out1 + (size_t)node * HIDDEN + le * 8;
    *(float4*)(op + 0) = q0;
    *(float4*)(op + 4) = q1;
}

// ---------- layer 2: relu/bias + 16->2 GEMM, pre-scaled by dinv ----------
__global__ __launch_bounds__(256) void k_mm2(const float* __restrict__ out1,
                                             const float* __restrict__ b1,
                                             const float* __restrict__ W2,
                                             const float* __restrict__ dinv,
                                             float2* __restrict__ hs2) {
    int n = blockIdx.x * 256 + threadIdx.x;
    if (n >= NPAD) return;
    if (n >= N_NODES) {                        // zero pad rows incl. DUMMY
        float2 z = {0.f, 0.f};
        hs2[n] = z;
        return;
    }
    float a0 = 0.f, a1 = 0.f;
    #pragma unroll
    for (int kk = 0; kk < HIDDEN; ++kk) {
        float v = fmaxf(out1[(size_t)n * HIDDEN + kk] + b1[kk], 0.f);  // out1 already has dinv_d
        a0 = fmaf(v, W2[kk * F_OUT + 0], a0);
        a1 = fmaf(v, W2[kk * F_OUT + 1], a1);
    }
    float dv = dinv[n];
    float2 h2; h2.x = a0 * dv; h2.y = a1 * dv;
    hs2[n] = h2;
}

// ---------- layer-2 aggregation + finalize: 1 lane/node, register acc ----------
__global__ __launch_bounds__(256) void k_agg2(const unsigned* __restrict__ adj2,
                                              const int* __restrict__ rowstart,
                                              const char* __restrict__ hs2,
                                              const float* __restrict__ dinv,
                                              const float* __restrict__ b2,
                                              float2* __restrict__ out) {
    int node = blockIdx.x * 256 + threadIdx.x;
    if (node >= N_NODES) return;
    int rs = rowstart[node], re = rowstart[node + 1];
    unsigned dummy_off = DUMMY_E * 8u;

    float a0 = 0.f, a1 = 0.f;
    f32x2 w0, w1, w2, w3, w4, w5, w6, w7;

#define GL2(dst, o) asm volatile("global_load_dwordx2 %0, %1, %2" \
    : "=v"(dst) : "v"(o), "s"(hs2) : "memory");

    for (int bs = rs; bs < re; bs += 8) {
        const unsigned* ap = adj2 + bs;
        unsigned j0 = ap[0], j1 = ap[1], j2 = ap[2], j3 = ap[3];
        unsigned j4 = ap[4], j5 = ap[5], j6 = ap[6], j7 = ap[7];
        unsigned o0 = (bs + 0 < re) ? (j0 << 3) : dummy_off;
        unsigned o1 = (bs + 1 < re) ? (j1 << 3) : dummy_off;
        unsigned o2 = (bs + 2 < re) ? (j2 << 3) : dummy_off;
        unsigned o3 = (bs + 3 < re) ? (j3 << 3) : dummy_off;
        unsigned o4 = (bs + 4 < re) ? (j4 << 3) : dummy_off;
        unsigned o5 = (bs + 5 < re) ? (j5 << 3) : dummy_off;
        unsigned o6 = (bs + 6 < re) ? (j6 << 3) : dummy_off;
        unsigned o7 = (bs + 7 < re) ? (j7 << 3) : dummy_off;
        GL2(w0, o0) GL2(w1, o1) GL2(w2, o2) GL2(w3, o3)
        GL2(w4, o4) GL2(w5, o5) GL2(w6, o6) GL2(w7, o7)
        asm volatile("s_waitcnt vmcnt(0)" ::: "memory");
        __builtin_amdgcn_sched_barrier(0);
        a0 += w0[0] + w1[0] + w2[0] + w3[0] + w4[0] + w5[0] + w6[0] + w7[0];
        a1 += w0[1] + w1[1] + w2[1] + w3[1] + w4[1] + w5[1] + w6[1] + w7[1];
    }
    const float2* h2p = (const float2*)hs2;
    float2 selfv = h2p[node];
    float dv = dinv[node];
    float2 r;
    r.x = fmaf(dv, a0 + selfv.x, b2[0]);
    r.y = fmaf(dv, a1 + selfv.y, b2[1]);
    out[node] = r;
}

// ---------- launcher ----------
extern "C" void kernel_launch(void* const* d_in, const int* in_sizes, int n_in,
                              void* d_out, int out_size, void* d_ws, size_t ws_size,
                              hipStream_t stream) {
    const float* x   = (const float*)d_in[0];
    const int*   ei  = (const int*)d_in[1];
    const int*   srcv = ei;
    const int*   dstv = ei + N_EDGES;
    const float* W1  = (const float*)d_in[2];
    const float* b1  = (const float*)d_in[3];
    const float* W2  = (const float*)d_in[4];
    const float* b2  = (const float*)d_in[5];
    float* out = (float*)d_out;

    char* w = (char*)d_ws;
    unsigned* adj        = (unsigned*)w;  w += (size_t)N_EDGES * 4;        // 12.8 MB (dead after sortbucket)
    float*    out1       = (float*)adj;                                    // alias: used only after sortbucket
    unsigned* adj2       = (unsigned*)w;  w += (size_t)(N_EDGES + 8) * 4;  // 12.8 MB + pad
    unsigned* blockHist  = (unsigned*)w;  w += (size_t)NB * G * 4;         // 1.6 MB
    unsigned* total      = (unsigned*)w;  w += (size_t)NB * 4;
    unsigned* bucketBase = (unsigned*)w;  w += (size_t)(NB + 1) * 4;
    int*      rowstart   = (int*)w;       w += (size_t)(N_NODES + 1) * 4;  // 0.4 MB
    w = (char*)(((size_t)w + 15) & ~(size_t)15);
    float* dinv  = (float*)w;  w += (size_t)N_NODES * 4;                   // 0.4 MB
    char*  hs    = w;          w += (size_t)NPAD * HIDDEN * 2;             // 3.2 MB fp16
    float* hs2   = (float*)w;                                              // 0.8 MB

    k_hist        <<<G, 256, 0, stream>>>(dstv, blockHist);
    k_scan_blocks <<<NB, G, 0, stream>>>(blockHist, total);
    k_scan_buckets<<<1, 1024, 0, stream>>>(total, bucketBase, rowstart);
    k_scatter     <<<G, 256, 0, stream>>>(srcv, dstv, blockHist, bucketBase, adj);
    k_sortbucket  <<<NB, 256, 0, stream>>>(adj, bucketBase, adj2, rowstart, dinv);
    k_mm1         <<<NPAD / MM1_NODES, 256, 0, stream>>>(x, W1, dinv, (half4*)hs);
    k_agg1        <<<(2 * NPAD) / 256, 256, 0, stream>>>(adj2, rowstart, hs, dinv, out1);
    k_mm2         <<<(NPAD + 255) / 256, 256, 0, stream>>>(out1, b1, W2, dinv, (float2*)hs2);
    k_agg2        <<<(NPAD + 255) / 256, 256, 0, stream>>>(adj2, rowstart, (const char*)hs2,
                                                           dinv, b2, (float2*)out);
}

// Round 8
// 126.768 us; speedup vs baseline: 4.3346x; 1.0906x over previous
//
#include <hip/hip_runtime.h>

#define N_NODES 100000
#define N_EDGES 3200000
#define F_IN    128
#define HIDDEN  16
#define F_OUT   2

#define BSZ     256                  // nodes per bucket
#define NB      391                  // ceil(N_NODES / BSZ)
#define NPAD    (NB * BSZ)           // 100096 padded node rows
#define G       512                  // edge-partition blocks for hist/scatter
#define EPB     (N_EDGES / G)        // 6250 edges per partition (exact, even)
#define DUMMY_E 100000u              // zeroed pad row used for clamped slots

typedef float  f32x4 __attribute__((ext_vector_type(4)));
typedef float  f32x2 __attribute__((ext_vector_type(2)));
typedef _Float16 half8 __attribute__((ext_vector_type(8)));
typedef _Float16 half4 __attribute__((ext_vector_type(4)));

// ---------- P1: per-partition bucket histogram (int2 loads, 2 sub-hists) ----------
__global__ __launch_bounds__(256) void k_hist(const int* __restrict__ dst,
                                              unsigned* __restrict__ blockHist) {
    __shared__ unsigned h0[NB];
    __shared__ unsigned h1[NB];
    int t = threadIdx.x, g = blockIdx.x;
    for (int i = t; i < NB; i += 256) { h0[i] = 0u; h1[i] = 0u; }
    __syncthreads();
    const int2* d2 = (const int2*)(dst + g * EPB);
    unsigned* myh = (t & 1) ? h1 : h0;
    for (int i = t; i < EPB / 2; i += 256) {
        int2 v = d2[i];
        atomicAdd(&myh[(unsigned)v.x >> 8], 1u);
        atomicAdd(&myh[(unsigned)v.y >> 8], 1u);
    }
    __syncthreads();
    for (int i = t; i < NB; i += 256) blockHist[i * G + g] = h0[i] + h1[i];
}

// ---------- P2: per-bucket exclusive scan over partitions ----------
__global__ __launch_bounds__(G) void k_scan_blocks(unsigned* __restrict__ blockHist,
                                                   unsigned* __restrict__ total) {
    __shared__ unsigned s[G];
    int b = blockIdx.x, t = threadIdx.x;
    unsigned v = blockHist[b * G + t];
    s[t] = v;
    __syncthreads();
    for (int off = 1; off < G; off <<= 1) {
        unsigned xv = (t >= off) ? s[t - off] : 0u;
        __syncthreads();
        s[t] += xv;
        __syncthreads();
    }
    blockHist[b * G + t] = s[t] - v;
    if (t == G - 1) total[b] = s[t];
}

// ---------- P2c: exclusive scan of bucket totals ----------
__global__ __launch_bounds__(512) void k_scan_buckets(const unsigned* __restrict__ total,
                                                      unsigned* __restrict__ bucketBase,
                                                      int* __restrict__ rowstart) {
    __shared__ unsigned s[512];
    int t = threadIdx.x;
    unsigned v = (t < NB) ? total[t] : 0u;
    s[t] = v;
    __syncthreads();
    for (int off = 1; off < 512; off <<= 1) {
        unsigned xv = (t >= off) ? s[t - off] : 0u;
        __syncthreads();
        s[t] += xv;
        __syncthreads();
    }
    if (t < NB) bucketBase[t] = s[t] - v;
    if (t == 511) {
        bucketBase[NB] = s[t];                 // == N_EDGES
        rowstart[N_NODES] = (int)s[t];
    }
}

// ---------- P3: LDS counting-sort scatter -> bucket-sorted adjacency ----------
// entry: (dst & 255) << 17 | src
__global__ __launch_bounds__(256) void k_scatter(const int* __restrict__ src,
                                                 const int* __restrict__ dst,
                                                 const unsigned* __restrict__ blockHist,
                                                 const unsigned* __restrict__ bucketBase,
                                                 unsigned* __restrict__ adj) {
    __shared__ unsigned stage[EPB];            // 25.0 KB
    __shared__ unsigned short stage_b[EPB];    // 12.5 KB
    __shared__ unsigned hist[NB];              // cursor
    __shared__ unsigned h1[NB];                // sub-hist
    __shared__ unsigned lstart[NB];
    __shared__ unsigned gbase[NB];
    __shared__ unsigned ssum[256];
    int t = threadIdx.x, g = blockIdx.x;
    for (int i = t; i < NB; i += 256) {
        hist[i] = 0u; h1[i] = 0u;
        gbase[i] = bucketBase[i] + blockHist[i * G + g];
    }
    __syncthreads();
    const int2* s2 = (const int2*)(src + g * EPB);
    const int2* d2 = (const int2*)(dst + g * EPB);
    // phase 1: local histogram (2 sub-hists)
    unsigned* myh = (t & 1) ? h1 : hist;
    for (int i = t; i < EPB / 2; i += 256) {
        int2 v = d2[i];
        atomicAdd(&myh[(unsigned)v.x >> 8], 1u);
        atomicAdd(&myh[(unsigned)v.y >> 8], 1u);
    }
    __syncthreads();
    // phase 2: merge + exclusive scan -> lstart; hist becomes cursor
    int i0 = t * 2;
    unsigned v0 = (i0 + 0 < NB) ? hist[i0 + 0] + h1[i0 + 0] : 0u;
    unsigned v1 = (i0 + 1 < NB) ? hist[i0 + 1] + h1[i0 + 1] : 0u;
    unsigned my = v0 + v1;
    ssum[t] = my;
    __syncthreads();
    for (int off = 1; off < 256; off <<= 1) {
        unsigned xv = (t >= off) ? ssum[t - off] : 0u;
        __syncthreads();
        ssum[t] += xv;
        __syncthreads();
    }
    unsigned e0 = ssum[t] - my;
    __syncthreads();
    unsigned e1 = e0 + v0;
    if (i0 + 0 < NB) { lstart[i0 + 0] = e0; hist[i0 + 0] = e0; }
    if (i0 + 1 < NB) { lstart[i0 + 1] = e1; hist[i0 + 1] = e1; }
    __syncthreads();
    // phase 3: stage entries bucket-ordered in LDS
    for (int i = t; i < EPB / 2; i += 256) {
        int2 sv = s2[i], dv = d2[i];
        unsigned bkt0 = (unsigned)dv.x >> 8;
        unsigned pos0 = atomicAdd(&hist[bkt0], 1u);
        stage[pos0] = ((unsigned)(dv.x & 255) << 17) | (unsigned)sv.x;
        stage_b[pos0] = (unsigned short)bkt0;
        unsigned bkt1 = (unsigned)dv.y >> 8;
        unsigned pos1 = atomicAdd(&hist[bkt1], 1u);
        stage[pos1] = ((unsigned)(dv.y & 255) << 17) | (unsigned)sv.y;
        stage_b[pos1] = (unsigned short)bkt1;
    }
    __syncthreads();
    // phase 4: grouped global writes (runs of ~16 = full 64B lines)
    for (int j = t; j < EPB; j += 256) {
        unsigned bkt = stage_b[j];
        adj[gbase[bkt] + (j - lstart[bkt])] = stage[j];
    }
}

// ---------- P4: in-bucket counting sort -> CSR (adj2 = src only), rowstart, dinv ----------
__global__ __launch_bounds__(256) void k_sortbucket(const unsigned* __restrict__ adj,
                                                    const unsigned* __restrict__ bucketBase,
                                                    unsigned* __restrict__ adj2,
                                                    int* __restrict__ rowstart,
                                                    float* __restrict__ dinv) {
    __shared__ unsigned hist[BSZ];
    __shared__ unsigned sc[BSZ];
    __shared__ unsigned cur[BSZ];
    int b = blockIdx.x, t = threadIdx.x;
    hist[t] = 0u;
    __syncthreads();
    int e0 = (int)bucketBase[b], e1 = (int)bucketBase[b + 1];
    for (int i = e0 + t; i < e1; i += 256) atomicAdd(&hist[adj[i] >> 17], 1u);
    __syncthreads();
    sc[t] = hist[t];
    __syncthreads();
    for (int off = 1; off < BSZ; off <<= 1) {
        unsigned a = (t >= off) ? sc[t - off] : 0u;
        __syncthreads();
        sc[t] += a;
        __syncthreads();
    }
    unsigned excl = sc[t] - hist[t];
    cur[t] = (unsigned)e0 + excl;
    int node = b * BSZ + t;
    if (node < N_NODES) {
        rowstart[node] = e0 + (int)excl;
        dinv[node] = rsqrtf((float)(hist[t] + 1u));
    }
    __syncthreads();
    for (int i = e0 + t; i < e1; i += 256) {
        unsigned v = adj[i];
        unsigned pos = atomicAdd(&cur[v >> 17], 1u);
        adj2[pos] = v & 0x1FFFFu;
    }
}

// ---------- layer-1 GEMM: hs(fp16) = (x @ W1) * dinv ----------
#define MM1_NODES 64
#define SXP 132
__global__ __launch_bounds__(256) void k_mm1(const float* __restrict__ x,
                                             const float* __restrict__ W1,
                                             const float* __restrict__ dinv,
                                             half4* __restrict__ hs) {
    __shared__ float sW[F_IN * HIDDEN];       // 8 KB
    __shared__ float sX[MM1_NODES * SXP];     // 33 KB
    int t = threadIdx.x;
    for (int i = t; i < F_IN * HIDDEN; i += 256) sW[i] = W1[i];
    int node0 = blockIdx.x * MM1_NODES;
    const float4* xv = (const float4*)(x + (size_t)node0 * F_IN);
    int maxv = (N_NODES - node0) * (F_IN / 4);
    if (maxv < 0) maxv = 0;
    for (int i = t; i < MM1_NODES * (F_IN / 4); i += 256) {
        if (i < maxv) {
            int nl = i >> 5, f4 = i & 31;
            ((float4*)(sX + nl * SXP))[f4] = xv[i];
        }
    }
    __syncthreads();
    int lane4 = t & 3;
    int nl = t >> 2;
    int n = node0 + nl;
    if (n >= NPAD) return;
    if (n >= N_NODES) {                       // zero pad rows incl. DUMMY row
        half4 hz = {(_Float16)0.f, (_Float16)0.f, (_Float16)0.f, (_Float16)0.f};
        hs[(size_t)n * 4 + lane4] = hz;
        return;
    }
    const float4* sWv = (const float4*)sW;
    float4 a = {0.f, 0.f, 0.f, 0.f};
    #pragma unroll 8
    for (int f = 0; f < F_IN; ++f) {
        float xval = sX[nl * SXP + f];
        float4 w = sWv[f * 4 + lane4];
        a.x = fmaf(xval, w.x, a.x);
        a.y = fmaf(xval, w.y, a.y);
        a.z = fmaf(xval, w.z, a.z);
        a.w = fmaf(xval, w.w, a.w);
    }
    float dv = dinv[n];
    half4 h; h[0] = (_Float16)(a.x * dv); h[1] = (_Float16)(a.y * dv);
    h[2] = (_Float16)(a.z * dv); h[3] = (_Float16)(a.w * dv);
    hs[(size_t)n * 4 + lane4] = h;
}

// ---------- layer-1 aggregation + FUSED layer-2 matmul ----------
// 2 lanes per node; each lane owns 8 fp16 channels. After the segment scan,
// relu/bias + 16->2 GEMM is done in-register with a __shfl_xor(1) pair-sum.
__global__ __launch_bounds__(256) void k_agg1(const unsigned* __restrict__ adj2,
                                              const int* __restrict__ rowstart,
                                              const char* __restrict__ hs,
                                              const float* __restrict__ dinv,
                                              const float* __restrict__ b1,
                                              const float* __restrict__ W2,
                                              float2* __restrict__ hs2) {
    int g = blockIdx.x * 256 + threadIdx.x;
    int node = g >> 1, le = g & 1;
    if (node >= N_NODES) {                     // zero pad rows incl. DUMMY
        if (le == 0 && node < NPAD) { float2 z = {0.f, 0.f}; hs2[node] = z; }
        return;
    }
    int rs = rowstart[node], re = rowstart[node + 1];
    unsigned le16 = (unsigned)le * 16u;
    unsigned dummy_off = DUMMY_E * 32u + le16;

    float a0 = 0.f, a1 = 0.f, a2 = 0.f, a3 = 0.f, a4 = 0.f, a5 = 0.f, a6 = 0.f, a7 = 0.f;
    f32x4 w0, w1, w2, w3, w4, w5, w6, w7;

#define GL1(dst, o) asm volatile("global_load_dwordx4 %0, %1, %2" \
    : "=v"(dst) : "v"(o), "s"(hs) : "memory");
#define AC1(w_) { half8 h8; __builtin_memcpy(&h8, &w_, 16); \
    a0 += (float)h8[0]; a1 += (float)h8[1]; a2 += (float)h8[2]; a3 += (float)h8[3]; \
    a4 += (float)h8[4]; a5 += (float)h8[5]; a6 += (float)h8[6]; a7 += (float)h8[7]; }

    for (int bs = rs; bs < re; bs += 8) {
        const unsigned* ap = adj2 + bs;        // adj2 padded by 8 -> safe reads
        unsigned j0 = ap[0], j1 = ap[1], j2 = ap[2], j3 = ap[3];
        unsigned j4 = ap[4], j5 = ap[5], j6 = ap[6], j7 = ap[7];
        unsigned o0 = (bs + 0 < re) ? (j0 << 5) + le16 : dummy_off;
        unsigned o1 = (bs + 1 < re) ? (j1 << 5) + le16 : dummy_off;
        unsigned o2 = (bs + 2 < re) ? (j2 << 5) + le16 : dummy_off;
        unsigned o3 = (bs + 3 < re) ? (j3 << 5) + le16 : dummy_off;
        unsigned o4 = (bs + 4 < re) ? (j4 << 5) + le16 : dummy_off;
        unsigned o5 = (bs + 5 < re) ? (j5 << 5) + le16 : dummy_off;
        unsigned o6 = (bs + 6 < re) ? (j6 << 5) + le16 : dummy_off;
        unsigned o7 = (bs + 7 < re) ? (j7 << 5) + le16 : dummy_off;
        GL1(w0, o0) GL1(w1, o1) GL1(w2, o2) GL1(w3, o3)
        GL1(w4, o4) GL1(w5, o5) GL1(w6, o6) GL1(w7, o7)
        asm volatile("s_waitcnt vmcnt(0)" ::: "memory");
        __builtin_amdgcn_sched_barrier(0);
        AC1(w0) AC1(w1) AC1(w2) AC1(w3) AC1(w4) AC1(w5) AC1(w6) AC1(w7)
    }
    // self term + dinv scale -> this lane's 8 out1 channels
    const _Float16* selfrow = (const _Float16*)(hs + (size_t)node * 32 + le16);
    float dv = dinv[node];
    float q0 = dv * (a0 + (float)selfrow[0]), q1 = dv * (a1 + (float)selfrow[1]);
    float q2 = dv * (a2 + (float)selfrow[2]), q3 = dv * (a3 + (float)selfrow[3]);
    float q4 = dv * (a4 + (float)selfrow[4]), q5 = dv * (a5 + (float)selfrow[5]);
    float q6 = dv * (a6 + (float)selfrow[6]), q7 = dv * (a7 + (float)selfrow[7]);
    // fused mm2: relu(q + b1) @ W2 over this lane's 8 channels
    const float4* b1v = (const float4*)(b1 + le * 8);
    float4 ba = b1v[0], bb = b1v[1];
    const float4* w2v = (const float4*)(W2 + le * 16);   // [k][2] floats for k in lane's range
    float4 wA = w2v[0], wB = w2v[1], wC = w2v[2], wD = w2v[3];
    float p0 = 0.f, p1 = 0.f, r;
    r = fmaxf(q0 + ba.x, 0.f); p0 = fmaf(r, wA.x, p0); p1 = fmaf(r, wA.y, p1);
    r = fmaxf(q1 + ba.y, 0.f); p0 = fmaf(r, wA.z, p0); p1 = fmaf(r, wA.w, p1);
    r = fmaxf(q2 + ba.z, 0.f); p0 = fmaf(r, wB.x, p0); p1 = fmaf(r, wB.y, p1);
    r = fmaxf(q3 + ba.w, 0.f); p0 = fmaf(r, wB.z, p0); p1 = fmaf(r, wB.w, p1);
    r = fmaxf(q4 + bb.x, 0.f); p0 = fmaf(r, wC.x, p0); p1 = fmaf(r, wC.y, p1);
    r = fmaxf(q5 + bb.y, 0.f); p0 = fmaf(r, wC.z, p0); p1 = fmaf(r, wC.w, p1);
    r = fmaxf(q6 + bb.z, 0.f); p0 = fmaf(r, wD.x, p0); p1 = fmaf(r, wD.y, p1);
    r = fmaxf(q7 + bb.w, 0.f); p0 = fmaf(r, wD.z, p0); p1 = fmaf(r, wD.w, p1);
    p0 += __shfl_xor(p0, 1);
    p1 += __shfl_xor(p1, 1);
    if (le == 0) {
        float2 h2; h2.x = p0 * dv; h2.y = p1 * dv;
        hs2[node] = h2;
    }
}

// ---------- layer-2 aggregation + finalize: 1 lane/node, register acc ----------
__global__ __launch_bounds__(256) void k_agg2(const unsigned* __restrict__ adj2,
                                              const int* __restrict__ rowstart,
                                              const char* __restrict__ hs2,
                                              const float* __restrict__ dinv,
                                              const float* __restrict__ b2,
                                              float2* __restrict__ out) {
    int node = blockIdx.x * 256 + threadIdx.x;
    if (node >= N_NODES) return;
    int rs = rowstart[node], re = rowstart[node + 1];
    unsigned dummy_off = DUMMY_E * 8u;

    float a0 = 0.f, a1 = 0.f;
    f32x2 w0, w1, w2, w3, w4, w5, w6, w7;

#define GL2(dst, o) asm volatile("global_load_dwordx2 %0, %1, %2" \
    : "=v"(dst) : "v"(o), "s"(hs2) : "memory");

    for (int bs = rs; bs < re; bs += 8) {
        const unsigned* ap = adj2 + bs;
        unsigned j0 = ap[0], j1 = ap[1], j2 = ap[2], j3 = ap[3];
        unsigned j4 = ap[4], j5 = ap[5], j6 = ap[6], j7 = ap[7];
        unsigned o0 = (bs + 0 < re) ? (j0 << 3) : dummy_off;
        unsigned o1 = (bs + 1 < re) ? (j1 << 3) : dummy_off;
        unsigned o2 = (bs + 2 < re) ? (j2 << 3) : dummy_off;
        unsigned o3 = (bs + 3 < re) ? (j3 << 3) : dummy_off;
        unsigned o4 = (bs + 4 < re) ? (j4 << 3) : dummy_off;
        unsigned o5 = (bs + 5 < re) ? (j5 << 3) : dummy_off;
        unsigned o6 = (bs + 6 < re) ? (j6 << 3) : dummy_off;
        unsigned o7 = (bs + 7 < re) ? (j7 << 3) : dummy_off;
        GL2(w0, o0) GL2(w1, o1) GL2(w2, o2) GL2(w3, o3)
        GL2(w4, o4) GL2(w5, o5) GL2(w6, o6) GL2(w7, o7)
        asm volatile("s_waitcnt vmcnt(0)" ::: "memory");
        __builtin_amdgcn_sched_barrier(0);
        a0 += w0[0] + w1[0] + w2[0] + w3[0] + w4[0] + w5[0] + w6[0] + w7[0];
        a1 += w0[1] + w1[1] + w2[1] + w3[1] + w4[1] + w5[1] + w6[1] + w7[1];
    }
    const float2* h2p = (const float2*)hs2;
    float2 selfv = h2p[node];
    float dv = dinv[node];
    float2 r;
    r.x = fmaf(dv, a0 + selfv.x, b2[0]);
    r.y = fmaf(dv, a1 + selfv.y, b2[1]);
    out[node] = r;
}

// ---------- launcher ----------
extern "C" void kernel_launch(void* const* d_in, const int* in_sizes, int n_in,
                              void* d_out, int out_size, void* d_ws, size_t ws_size,
                              hipStream_t stream) {
    const float* x   = (const float*)d_in[0];
    const int*   ei  = (const int*)d_in[1];
    const int*   srcv = ei;
    const int*   dstv = ei + N_EDGES;
    const float* W1  = (const float*)d_in[2];
    const float* b1  = (const float*)d_in[3];
    const float* W2  = (const float*)d_in[4];
    const float* b2  = (const float*)d_in[5];
    float* out = (float*)d_out;

    char* w = (char*)d_ws;
    unsigned* adj        = (unsigned*)w;  w += (size_t)N_EDGES * 4;        // 12.8 MB
    unsigned* adj2       = (unsigned*)w;  w += (size_t)(N_EDGES + 8) * 4;  // 12.8 MB + pad
    unsigned* blockHist  = (unsigned*)w;  w += (size_t)NB * G * 4;         // 0.8 MB
    unsigned* total      = (unsigned*)w;  w += (size_t)NB * 4;
    unsigned* bucketBase = (unsigned*)w;  w += (size_t)(NB + 1) * 4;
    int*      rowstart   = (int*)w;       w += (size_t)(N_NODES + 1) * 4;  // 0.4 MB
    w = (char*)(((size_t)w + 15) & ~(size_t)15);
    float* dinv  = (float*)w;  w += (size_t)N_NODES * 4;                   // 0.4 MB
    char*  hs    = w;          w += (size_t)NPAD * HIDDEN * 2;             // 3.2 MB fp16
    float* hs2   = (float*)w;                                              // 0.8 MB

    k_hist        <<<G, 256, 0, stream>>>(dstv, blockHist);
    k_scan_blocks <<<NB, G, 0, stream>>>(blockHist, total);
    k_scan_buckets<<<1, 512, 0, stream>>>(total, bucketBase, rowstart);
    k_scatter     <<<G, 256, 0, stream>>>(srcv, dstv, blockHist, bucketBase, adj);
    k_sortbucket  <<<NB, 256, 0, stream>>>(adj, bucketBase, adj2, rowstart, dinv);
    k_mm1         <<<NPAD / MM1_NODES, 256, 0, stream>>>(x, W1, dinv, (half4*)hs);
    k_agg1        <<<(2 * NPAD) / 256, 256, 0, stream>>>(adj2, rowstart, hs, dinv,
                                                         b1, W2, (float2*)hs2);
    k_agg2        <<<(NPAD + 255) / 256, 256, 0, stream>>>(adj2, rowstart, (const char*)hs2,
                                                           dinv, b2, (float2*)out);
}